// Round 4
// baseline (189.811 us; speedup 1.0000x reference)
//
#include <hip/hip_runtime.h>

#define NBINS 101
#define NB2 (2 * NBINS)   // 202 bins total (pos + neg)
#define BT 128            // block tile (pairs tile is BT x BT)
#define NTHREADS 256
#define NCOPY 16          // LDS histogram replicas, one per lane&15

typedef _Float16 half8 __attribute__((ext_vector_type(8)));
typedef float floatx4 __attribute__((ext_vector_type(4)));

// ---------------------------------------------------------------------------
// One block per 128x128 upper-triangular tile. f16 MFMA computes the
// similarity tile; pairs are binned with native fp32 LDS atomics
// (unsafeAtomicAdd -> ds_add_f32). NO global atomics anywhere: each block
// plain-stores its 202 merged bins to a private partials[block] row.
// (R3 evidence: WRITE_SIZE == #global_atomics x 4B => global fp32 atomics
// are HBM-side RMWs; the returning g_count atomic serialized 528 blocks at
// ~200ns each ~= the 143us of idle time. All removed.)
// ---------------------------------------------------------------------------
__global__ __launch_bounds__(NTHREADS, 2)
void hist_pairs_kernel(const float* __restrict__ feats,
                       const int* __restrict__ classes,
                       float* __restrict__ partials,  // [nblocks][NB2]
                       int ntiles) {
    __shared__ __align__(16) _Float16 As[16][BT][8];   // [K/8][row][8 halves]
    __shared__ __align__(16) _Float16 Bs[16][BT][8];
    __shared__ float lhist[NB2][NCOPY];
    __shared__ __align__(16) int clsA[BT];
    __shared__ __align__(16) int clsB[BT];

    // blockIdx -> (ti, tj), ti <= tj, row-major over the upper triangle
    int b = blockIdx.x;
    int ti = 0, rem = b;
    while (rem >= ntiles - ti) { rem -= ntiles - ti; ++ti; }
    int tj = ti + rem;
    const int i0 = ti * BT, j0 = tj * BT;
    const int tid = threadIdx.x;

    // zero local histograms
    for (int t = tid; t < NB2 * NCOPY; t += NTHREADS)
        (&lhist[0][0])[t] = 0.0f;

    // stage both tiles fp32 -> f16, K-major chunks of 8
    {
        const int row = tid >> 1;
        const int c0 = (tid & 1) * 64;
        const float* pa = &feats[(size_t)(i0 + row) * 128 + c0];
        const float* pb = &feats[(size_t)(j0 + row) * 128 + c0];
        #pragma unroll
        for (int c = 0; c < 64; c += 8) {
            float4 f0 = *(const float4*)&pa[c];
            float4 f1 = *(const float4*)&pa[c + 4];
            half8 h;
            h[0] = (_Float16)f0.x; h[1] = (_Float16)f0.y;
            h[2] = (_Float16)f0.z; h[3] = (_Float16)f0.w;
            h[4] = (_Float16)f1.x; h[5] = (_Float16)f1.y;
            h[6] = (_Float16)f1.z; h[7] = (_Float16)f1.w;
            *(half8*)&As[(c0 + c) >> 3][row][0] = h;
            f0 = *(const float4*)&pb[c];
            f1 = *(const float4*)&pb[c + 4];
            h[0] = (_Float16)f0.x; h[1] = (_Float16)f0.y;
            h[2] = (_Float16)f0.z; h[3] = (_Float16)f0.w;
            h[4] = (_Float16)f1.x; h[5] = (_Float16)f1.y;
            h[6] = (_Float16)f1.z; h[7] = (_Float16)f1.w;
            *(half8*)&Bs[(c0 + c) >> 3][row][0] = h;
        }
    }
    if (tid < BT) clsA[tid] = classes[i0 + tid];
    else          clsB[tid - BT] = classes[j0 + tid - BT];
    __syncthreads();

    // each wave owns a 64x64 sub-tile: 4x4 grid of 16x16 MFMA tiles, K=128
    const int wave = tid >> 6;
    const int lane = tid & 63;
    const int wm = (wave >> 1) * 64;
    const int wn = (wave & 1) * 64;
    const int lr = lane & 15;
    const int quad = lane >> 4;

    floatx4 acc[4][4] = {};
    #pragma unroll
    for (int ks = 0; ks < 128; ks += 32) {
        half8 af[4], bf[4];
        #pragma unroll
        for (int mi = 0; mi < 4; ++mi)
            af[mi] = *(const half8*)&As[(ks >> 3) + quad][wm + mi * 16 + lr][0];
        #pragma unroll
        for (int ni = 0; ni < 4; ++ni)
            bf[ni] = *(const half8*)&Bs[(ks >> 3) + quad][wn + ni * 16 + lr][0];
        #pragma unroll
        for (int mi = 0; mi < 4; ++mi)
            #pragma unroll
            for (int ni = 0; ni < 4; ++ni)
                acc[mi][ni] = __builtin_amdgcn_mfma_f32_16x16x32_f16(
                    af[mi], bf[ni], acc[mi][ni], 0, 0, 0);
    }

    // classes for this lane's C fragment rows/cols
    int cA[4][4], cB[4];
    #pragma unroll
    for (int mi = 0; mi < 4; ++mi) {
        int4 c4 = *(const int4*)&clsA[wm + mi * 16 + quad * 4];
        cA[mi][0] = c4.x; cA[mi][1] = c4.y; cA[mi][2] = c4.z; cA[mi][3] = c4.w;
    }
    #pragma unroll
    for (int ni = 0; ni < 4; ++ni) cB[ni] = clsB[wn + ni * 16 + lr];

    // binning: C-layout col = lane&15, row = quad*4 + reg
    const int copy = lane & (NCOPY - 1);
    const bool diag = (ti == tj);
    #pragma unroll
    for (int mi = 0; mi < 4; ++mi) {
        #pragma unroll
        for (int ni = 0; ni < 4; ++ni) {
            #pragma unroll
            for (int r = 0; r < 4; ++r) {
                const int li = wm + mi * 16 + quad * 4 + r;
                const int lj = wn + ni * 16 + lr;
                if (diag && li >= lj) continue;  // strict upper triangle
                float s = acc[mi][ni][r];
                float pos = (s + 1.0f) * 50.0f;  // (s+1)/step, step=0.02
                int idx = (int)floorf(pos);
                idx = idx < 0 ? 0 : (idx > NBINS - 1 ? NBINS - 1 : idx);
                float frac = pos - (float)idx;
                int hoff = (cA[mi][r] == cB[ni]) ? 0 : NBINS;
                unsafeAtomicAdd(&lhist[hoff + idx][copy], 1.0f - frac);
                int up = idx + 1 > NBINS - 1 ? NBINS - 1 : idx + 1;
                unsafeAtomicAdd(&lhist[hoff + up][copy], frac);
            }
        }
    }
    __syncthreads();

    // merge replicas -> plain coalesced store into this block's partials row
    float* prow = &partials[(size_t)b * NB2];
    for (int t = tid; t < NB2; t += NTHREADS) {
        float ssum = 0.0f;
        #pragma unroll
        for (int c = 0; c < NCOPY; ++c)
            ssum += lhist[t][(c + tid) & (NCOPY - 1)];
        prow[t] = ssum;
    }
}

// ---------------------------------------------------------------------------
// Sum 528 partial rows (coalesced, 5-way row split), then fp64 finalize:
// normalize, inclusive cumsum of pos, dot with neg.
// ---------------------------------------------------------------------------
__global__ __launch_bounds__(1024)
void reduce_finalize_kernel(const float* __restrict__ partials,
                            float* __restrict__ out, int nrows) {
    __shared__ float acc[5][NB2];
    __shared__ float h[NB2];
    const int t = threadIdx.x;
    const int g = t / NB2;          // group 0..4 (t >= 1010 idle)
    const int bin = t - g * NB2;
    if (g < 5) {
        float s = 0.0f;
        #pragma unroll 4
        for (int r = g; r < nrows; r += 5)
            s += partials[(size_t)r * NB2 + bin];
        acc[g][bin] = s;
    }
    __syncthreads();
    if (t < NB2)
        h[t] = acc[0][t] + acc[1][t] + acc[2][t] + acc[3][t] + acc[4][t];
    __syncthreads();
    if (t == 0) {
        double sp = 0.0, sn = 0.0;
        for (int k = 0; k < NBINS; ++k) { sp += h[k]; sn += h[NBINS + k]; }
        double isp = 1.0 / sp, isn = 1.0 / sn;
        double cdf = 0.0, res = 0.0;
        for (int k = 0; k < NBINS; ++k) {
            cdf += (double)h[k] * isp;                 // inclusive cumsum of pos
            res += (double)h[NBINS + k] * isn * cdf;   // dot with neg
        }
        out[0] = (float)res;
    }
}

extern "C" void kernel_launch(void* const* d_in, const int* in_sizes, int n_in,
                              void* d_out, int out_size, void* d_ws, size_t ws_size,
                              hipStream_t stream) {
    const float* feats   = (const float*)d_in[0];
    const int*   classes = (const int*)d_in[1];
    float* out      = (float*)d_out;
    float* partials = (float*)d_ws;            // [nblocks][202], plain stores

    int N = in_sizes[1];                       // 4096
    int ntiles = (N + BT - 1) / BT;            // 32
    int nblocks = ntiles * (ntiles + 1) / 2;   // 528

    hist_pairs_kernel<<<nblocks, NTHREADS, 0, stream>>>(feats, classes, partials, ntiles);
    reduce_finalize_kernel<<<1, 1024, 0, stream>>>(partials, out, nblocks);
}